// Round 4
// baseline (594.743 us; speedup 1.0000x reference)
//
#include <hip/hip_runtime.h>

#define NUM_NODES 100000
#define NODE_DIM 32

typedef float floatx4 __attribute__((ext_vector_type(4)));

// ---------------------------------------------------------------------------
// Kernel 1: zero the output accumulator (d_out) and the count buffer (d_ws).
// ---------------------------------------------------------------------------
__global__ void mp_zero_kernel(float4* __restrict__ out4,
                               float4* __restrict__ cnt4,
                               int n_out4, int n_cnt4) {
    int t = blockIdx.x * blockDim.x + threadIdx.x;
    if (t < n_out4) {
        out4[t] = make_float4(0.f, 0.f, 0.f, 0.f);
    }
    int u = t - n_out4;
    if (u >= 0 && u < n_cnt4) {
        cnt4[u] = make_float4(0.f, 0.f, 0.f, 0.f);
    }
}

// ---------------------------------------------------------------------------
// Kernel 2: per-edge messages + scatter-add, 2-edge-interleaved grid-stride.
// 8 lanes per group; lane j owns output features [4j,4j+3]. Each group
// processes edges (e, e+ngroups) as two independent load/FMA streams so the
// A-load stream has no dependency gap at edge boundaries. Next pair's
// edge_index + x rows are prefetched during compute. a_in loads nontemporal.
// ---------------------------------------------------------------------------
__global__ void mp_edge_kernel(const float* __restrict__ node_states,
                               const int* __restrict__ edge_index,
                               const floatx4* __restrict__ a4,
                               float* __restrict__ out_sum,
                               float* __restrict__ counts,
                               int n_edges) {
    int tid = blockIdx.x * blockDim.x + threadIdx.x;
    int j = tid & 7;
    int group = tid >> 3;
    int ngroups = (gridDim.x * blockDim.x) >> 3;
    int stride = ngroups * 2;

    int e0 = group;
    if (e0 >= n_edges) return;

    const float4* ns4 = reinterpret_cast<const float4*>(node_states);

    // pair state: e0 always valid inside loop; e1 clamped to e0 when invalid
    int e1t = e0 + ngroups;
    bool v1 = (e1t < n_edges);
    int e1 = v1 ? e1t : e0;

    int2 ei0 = *reinterpret_cast<const int2*>(edge_index + 2 * (size_t)e0);
    float4 x0 = ns4[(size_t)ei0.x * 8 + j];
    int2 ei1 = *reinterpret_cast<const int2*>(edge_index + 2 * (size_t)e1);
    float4 x1 = ns4[(size_t)ei1.x * 8 + j];

    for (;;) {
        // ---- prefetch next pair ----
        int f0 = e0 + stride;
        bool hasNext = (f0 < n_edges);
        int f1t = f0 + ngroups;
        bool nv1 = false;
        int f1 = f0;
        int2 ni0, ni1;
        float4 nx0, nx1;
        if (hasNext) {
            nv1 = (f1t < n_edges);
            f1 = nv1 ? f1t : f0;
            ni0 = *reinterpret_cast<const int2*>(edge_index + 2 * (size_t)f0);
            nx0 = ns4[(size_t)ni0.x * 8 + j];
            ni1 = *reinterpret_cast<const int2*>(edge_index + 2 * (size_t)f1);
            nx1 = ns4[(size_t)ni1.x * 8 + j];
        }

        // ---- compute both edges (independent streams) ----
        const floatx4* A0 = a4 + (size_t)e0 * 256;
        const floatx4* A1 = a4 + (size_t)e1 * 256;
        float xs0[4] = {x0.x, x0.y, x0.z, x0.w};
        float xs1[4] = {x1.x, x1.y, x1.z, x1.w};
        float4 acc0 = make_float4(0.f, 0.f, 0.f, 0.f);
        float4 acc1 = make_float4(0.f, 0.f, 0.f, 0.f);

#pragma unroll
        for (int d = 0; d < 32; ++d) {
            float xd0 = __shfl(xs0[d & 3], d >> 2, 8);
            float xd1 = __shfl(xs1[d & 3], d >> 2, 8);
            floatx4 a0 = __builtin_nontemporal_load(&A0[d * 8 + j]);
            floatx4 a1 = __builtin_nontemporal_load(&A1[d * 8 + j]);
            acc0.x = fmaf(xd0, a0.x, acc0.x);
            acc0.y = fmaf(xd0, a0.y, acc0.y);
            acc0.z = fmaf(xd0, a0.z, acc0.z);
            acc0.w = fmaf(xd0, a0.w, acc0.w);
            acc1.x = fmaf(xd1, a1.x, acc1.x);
            acc1.y = fmaf(xd1, a1.y, acc1.y);
            acc1.z = fmaf(xd1, a1.z, acc1.z);
            acc1.w = fmaf(xd1, a1.w, acc1.w);
        }

        // ---- scatter ----
        {
            float* o = out_sum + (size_t)ei0.y * NODE_DIM + j * 4;
            atomicAdd(o + 0, acc0.x);
            atomicAdd(o + 1, acc0.y);
            atomicAdd(o + 2, acc0.z);
            atomicAdd(o + 3, acc0.w);
            if (j == 0) atomicAdd(counts + ei0.y, 1.0f);
        }
        if (v1) {
            float* o = out_sum + (size_t)ei1.y * NODE_DIM + j * 4;
            atomicAdd(o + 0, acc1.x);
            atomicAdd(o + 1, acc1.y);
            atomicAdd(o + 2, acc1.z);
            atomicAdd(o + 3, acc1.w);
            if (j == 0) atomicAdd(counts + ei1.y, 1.0f);
        }

        if (!hasNext) break;
        e0 = f0; e1 = f1; v1 = nv1;
        ei0 = ni0; ei1 = ni1; x0 = nx0; x1 = nx1;
    }
}

// ---------------------------------------------------------------------------
// Kernel 3: out = relu(out / max(count,1) + bias)
// ---------------------------------------------------------------------------
__global__ void mp_finalize_kernel(float4* __restrict__ out4,
                                   const float* __restrict__ counts,
                                   const float4* __restrict__ bias4,
                                   int n_nodes) {
    int t = blockIdx.x * blockDim.x + threadIdx.x;
    if (t >= n_nodes * 8) return;
    int n = t >> 3;
    int j = t & 7;
    float c = fmaxf(counts[n], 1.0f);
    float inv = 1.0f / c;
    float4 s = out4[t];
    float4 b = bias4[j];
    float4 r;
    r.x = fmaxf(fmaf(s.x, inv, b.x), 0.f);
    r.y = fmaxf(fmaf(s.y, inv, b.y), 0.f);
    r.z = fmaxf(fmaf(s.z, inv, b.z), 0.f);
    r.w = fmaxf(fmaf(s.w, inv, b.w), 0.f);
    out4[t] = r;
}

extern "C" void kernel_launch(void* const* d_in, const int* in_sizes, int n_in,
                              void* d_out, int out_size, void* d_ws, size_t ws_size,
                              hipStream_t stream) {
    const float* node_states = (const float*)d_in[0];
    const int*   edge_index  = (const int*)d_in[1];
    const float* a_in        = (const float*)d_in[2];
    const float* bias        = (const float*)d_in[3];

    int n_edges = in_sizes[1] / 2;          // 500000
    int n_nodes = in_sizes[0] / NODE_DIM;   // 100000

    float* out_sum = (float*)d_out;          // accumulate sums in-place
    float* counts  = (float*)d_ws;           // n_nodes floats of scratch

    // 1) zero accumulators
    int n_out4 = n_nodes * (NODE_DIM / 4);   // 800000
    int n_cnt4 = (n_nodes + 3) / 4;          // 25000
    {
        int total = n_out4 + n_cnt4;
        int blocks = (total + 255) / 256;
        mp_zero_kernel<<<blocks, 256, 0, stream>>>(
            (float4*)out_sum, (float4*)counts, n_out4, n_cnt4);
    }

    // 2) edge messages + scatter (2-edge interleaved grid-stride)
    {
        int blocks = 1024;  // 32768 groups, pair-stride 65536 -> ~8 pair-iters
        mp_edge_kernel<<<blocks, 256, 0, stream>>>(
            node_states, edge_index, (const floatx4*)a_in,
            out_sum, counts, n_edges);
    }

    // 3) mean + bias + relu
    {
        int total = n_nodes * 8;
        int blocks = (total + 255) / 256;
        mp_finalize_kernel<<<blocks, 256, 0, stream>>>(
            (float4*)out_sum, counts, (const float4*)bias, n_nodes);
    }
}

// Round 5
// 398.430 us; speedup vs baseline: 1.4927x; 1.4927x over previous
//
#include <hip/hip_runtime.h>

#define NUM_NODES 100000
#define NODE_DIM 32

typedef float floatx4 __attribute__((ext_vector_type(4)));

// ---------------------------------------------------------------------------
// Kernel 1: zero the output accumulator (d_out) and the count buffer (d_ws).
// ---------------------------------------------------------------------------
__global__ void mp_zero_kernel(float4* __restrict__ out4,
                               float4* __restrict__ cnt4,
                               int n_out4, int n_cnt4) {
    int t = blockIdx.x * blockDim.x + threadIdx.x;
    if (t < n_out4) {
        out4[t] = make_float4(0.f, 0.f, 0.f, 0.f);
    }
    int u = t - n_out4;
    if (u >= 0 && u < n_cnt4) {
        cnt4[u] = make_float4(0.f, 0.f, 0.f, 0.f);
    }
}

// ---------------------------------------------------------------------------
// Kernel 2: per-edge message computation + scatter-add (R3 structure).
// Grid-stride: 8 lanes per edge-slot; lane j owns output features [4j,4j+3].
// Next edge's (edge_index, x) chain is prefetched while current edge's
// A-loads/FMAs execute. a_in is loaded nontemporally (streamed once).
// Scatter uses unsafeAtomicAdd -> hardware global_atomic_add_f32 (never a
// CAS loop).
// ---------------------------------------------------------------------------
__global__ void mp_edge_kernel(const float* __restrict__ node_states,
                               const int* __restrict__ edge_index,
                               const floatx4* __restrict__ a4,
                               float* __restrict__ out_sum,
                               float* __restrict__ counts,
                               int n_edges) {
    int tid = blockIdx.x * blockDim.x + threadIdx.x;
    int j = tid & 7;
    int group = tid >> 3;
    int ngroups = (gridDim.x * blockDim.x) >> 3;

    int e = group;
    if (e >= n_edges) return;

    // prologue: load first edge's index pair + x row
    int2 ei = *reinterpret_cast<const int2*>(edge_index + 2 * (size_t)e);
    float4 x4 = reinterpret_cast<const float4*>(node_states)[(size_t)ei.x * 8 + j];

    while (e < n_edges) {
        int en = e + ngroups;
        int2 ei_n;
        float4 x4_n;
        if (en < n_edges) {
            // prefetch next edge's chained loads; overlaps with A-loads + FMAs
            ei_n = *reinterpret_cast<const int2*>(edge_index + 2 * (size_t)en);
            x4_n = reinterpret_cast<const float4*>(node_states)[(size_t)ei_n.x * 8 + j];
        }

        float xs[4] = {x4.x, x4.y, x4.z, x4.w};
        const floatx4* A = a4 + (size_t)e * 256;  // 32x32 floats = 256 float4
        float4 acc = make_float4(0.f, 0.f, 0.f, 0.f);

#pragma unroll
        for (int d = 0; d < 32; ++d) {
            float xd = __shfl(xs[d & 3], d >> 2, 8);
            floatx4 a = __builtin_nontemporal_load(&A[d * 8 + j]);
            acc.x = fmaf(xd, a.x, acc.x);
            acc.y = fmaf(xd, a.y, acc.y);
            acc.z = fmaf(xd, a.z, acc.z);
            acc.w = fmaf(xd, a.w, acc.w);
        }

        int dst = ei.y;
        float* o = out_sum + (size_t)dst * NODE_DIM + j * 4;
        unsafeAtomicAdd(o + 0, acc.x);
        unsafeAtomicAdd(o + 1, acc.y);
        unsafeAtomicAdd(o + 2, acc.z);
        unsafeAtomicAdd(o + 3, acc.w);
        if (j == 0) unsafeAtomicAdd(counts + dst, 1.0f);

        e = en;
        ei = ei_n;
        x4 = x4_n;
    }
}

// ---------------------------------------------------------------------------
// Kernel 3: out = relu(out / max(count,1) + bias)
// ---------------------------------------------------------------------------
__global__ void mp_finalize_kernel(float4* __restrict__ out4,
                                   const float* __restrict__ counts,
                                   const float4* __restrict__ bias4,
                                   int n_nodes) {
    int t = blockIdx.x * blockDim.x + threadIdx.x;
    if (t >= n_nodes * 8) return;
    int n = t >> 3;
    int j = t & 7;
    float c = fmaxf(counts[n], 1.0f);
    float inv = 1.0f / c;
    float4 s = out4[t];
    float4 b = bias4[j];
    float4 r;
    r.x = fmaxf(fmaf(s.x, inv, b.x), 0.f);
    r.y = fmaxf(fmaf(s.y, inv, b.y), 0.f);
    r.z = fmaxf(fmaf(s.z, inv, b.z), 0.f);
    r.w = fmaxf(fmaf(s.w, inv, b.w), 0.f);
    out4[t] = r;
}

extern "C" void kernel_launch(void* const* d_in, const int* in_sizes, int n_in,
                              void* d_out, int out_size, void* d_ws, size_t ws_size,
                              hipStream_t stream) {
    const float* node_states = (const float*)d_in[0];
    const int*   edge_index  = (const int*)d_in[1];
    const float* a_in        = (const float*)d_in[2];
    const float* bias        = (const float*)d_in[3];

    int n_edges = in_sizes[1] / 2;          // 500000
    int n_nodes = in_sizes[0] / NODE_DIM;   // 100000

    float* out_sum = (float*)d_out;          // accumulate sums in-place
    float* counts  = (float*)d_ws;           // n_nodes floats of scratch

    // 1) zero accumulators
    int n_out4 = n_nodes * (NODE_DIM / 4);   // 800000
    int n_cnt4 = (n_nodes + 3) / 4;          // 25000
    {
        int total = n_out4 + n_cnt4;
        int blocks = (total + 255) / 256;
        mp_zero_kernel<<<blocks, 256, 0, stream>>>(
            (float4*)out_sum, (float4*)counts, n_out4, n_cnt4);
    }

    // 2) edge messages + scatter (grid-stride; ~8 edges per 8-lane group)
    {
        int blocks = 2048;  // 2048*256/8 = 65536 groups -> ~7.6 edges/group
        mp_edge_kernel<<<blocks, 256, 0, stream>>>(
            node_states, edge_index, (const floatx4*)a_in,
            out_sum, counts, n_edges);
    }

    // 3) mean + bias + relu
    {
        int total = n_nodes * 8;
        int blocks = (total + 255) / 256;
        mp_finalize_kernel<<<blocks, 256, 0, stream>>>(
            (float4*)out_sum, counts, (const float4*)bias, n_nodes);
    }
}